// Round 11
// baseline (400.430 us; speedup 1.0000x reference)
//
#include <hip/hip_runtime.h>

#define N_NODES 50000
#define N_EDGES 800000
#define N_RELS  8
#define NCOL    576          // 9 * 64 output cols (8 relations + self-loop)
#define BPACK_ELEMS (NCOL * 64)                          // 36864 bf16
#define NTILE   (N_NODES / 16)     // 3125 hw tiles

// bucketing: 64 nodes per bucket, bucket = dst >> 6
#define NPB     64
#define NBUK    782                // 782*64 = 50048 >= 50000
#define BUKCAP  1280               // lambda=1024, sigma=32 -> +8 sigma
#define ABLK    128                // abin blocks
#define ACHUNK  6250               // 128 * 6250 = 800000 exactly

typedef __attribute__((ext_vector_type(8))) short short8;
typedef __attribute__((ext_vector_type(4))) float f32x4;

static __device__ __forceinline__ short f2bf(float f) {
    unsigned u = __float_as_uint(f);
    unsigned r = (u + 0x7FFFu + ((u >> 16) & 1u)) >> 16;   // RNE
    return (short)r;
}
static __device__ __forceinline__ float bf2f(unsigned short b) {
    return __uint_as_float(((unsigned)b) << 16);
}

// ---------------------------------------------------------------------------
// Pre-pack B (8 rels + self-loop) into MFMA fragment order; also zeroes gcnt.
// grid = 196 blocks * 256 thr = 50176 >= BPACK_ELEMS.
// ---------------------------------------------------------------------------
__global__ __launch_bounds__(256) void k_bpack(const float* __restrict__ W,
                                               const float* __restrict__ lw,
                                               unsigned short* __restrict__ Bpack,
                                               int* __restrict__ gcnt) {
    const int id = blockIdx.x * 256 + threadIdx.x;
    if (id < NBUK) gcnt[id] = 0;
    if (id >= BPACK_ELEMS) return;
    const int e    = id & 7;
    const int lane = (id >> 3) & 63;
    const int g    = id >> 9;            // 0..71
    const int w    = g / 18;
    const int r18  = g - w * 18;
    const int t    = r18 >> 1;
    const int s    = r18 & 1;
    const int c0   = w * 144 + t * 16;
    const int rel  = c0 >> 6;
    const int cc   = (c0 & 63) + (lane & 15);
    const int kk   = s * 32 + (lane >> 4) * 8 + e;
    const float* Bp = (rel < 8) ? (W + (size_t)rel * 4096) : lw;
    Bpack[id] = (unsigned short)f2bf(Bp[(size_t)kk * 64 + cc]);
}

// ---------------------------------------------------------------------------
// MFMA transform: hw2[n][c] = sum_d h[n][d] * B[d][c]. One 16-node tile per
// block, grid = 3125. (Round-6 structure: swizzled LDS, coalesced copy-out.)
// ---------------------------------------------------------------------------
__global__ __launch_bounds__(256) void k_hw(const float* __restrict__ h,
                                            const unsigned short* __restrict__ Bpack,
                                            unsigned short* __restrict__ hw2) {
    const int lane  = threadIdx.x & 63;
    const int w     = threadIdx.x >> 6;
    const int l15   = lane & 15;
    const int lg    = lane >> 4;           // 0..3
    const int wcol0 = w * 144;
    const int n0    = blockIdx.x * 16;

    short8 barr[9][2];
#pragma unroll
    for (int t = 0; t < 9; ++t)
#pragma unroll
        for (int s = 0; s < 2; ++s)
            barr[t][s] = *(const short8*)(Bpack + ((size_t)(w * 18 + t * 2 + s) * 64 + lane) * 8);

    short8 afr[2];
    const float* hp = h + (size_t)(n0 + l15) * 64 + lg * 8;
#pragma unroll
    for (int s = 0; s < 2; ++s) {
        const float4 x = *(const float4*)(hp + s * 32);
        const float4 y = *(const float4*)(hp + s * 32 + 4);
        short8 a;
        a[0] = f2bf(x.x); a[1] = f2bf(x.y); a[2] = f2bf(x.z); a[3] = f2bf(x.w);
        a[4] = f2bf(y.x); a[5] = f2bf(y.y); a[6] = f2bf(y.z); a[7] = f2bf(y.w);
        afr[s] = a;
    }

    f32x4 acc[9];
#pragma unroll
    for (int t = 0; t < 9; ++t) {
        f32x4 c = {0.f, 0.f, 0.f, 0.f};
        c = __builtin_amdgcn_mfma_f32_16x16x32_bf16(afr[0], barr[t][0], c, 0, 0, 0);
        c = __builtin_amdgcn_mfma_f32_16x16x32_bf16(afr[1], barr[t][1], c, 0, 0, 0);
        acc[t] = c;
    }

    __shared__ unsigned short lds[16 * NCOL];   // 18.4 KB
#pragma unroll
    for (int t = 0; t < 9; ++t) {
        const int c = wcol0 + t * 16 + l15;
#pragma unroll
        for (int r = 0; r < 4; ++r) {
            const int row = lg * 4 + r;   // D: col=lane&15, row=lg*4+reg
            lds[row * NCOL + (c ^ (lg << 4))] = (unsigned short)f2bf(acc[t][r]);
        }
    }
    __syncthreads();

    const unsigned* ldsu = (const unsigned*)lds;       // pitch 288 u32
    unsigned* outu = (unsigned*)hw2;
#pragma unroll
    for (int i = threadIdx.x; i < 16 * 288; i += 256) {
        const int row = i / 288;
        const int cu  = i - row * 288;
        outu[(size_t)(n0 + row) * 288 + cu] = ldsu[row * 288 + (cu ^ ((row >> 2) << 3))];
    }
}

// ---------------------------------------------------------------------------
// Phase A: bucket-bin edges by dst>>6. Per block: LDS count -> one global
// atomic per bucket reserving a CONTIGUOUS run -> place records. The 8B
// scatter becomes ~64-128B runs: kills the one-line-per-record thrash that
// pinned WRITE_SIZE at ~48MB across rounds 7-10.
// rec.x = (dst&63)<<19 | (src*9+rel)  [19 bits: max 450008]; rec.y = norm.
// ---------------------------------------------------------------------------
__global__ __launch_bounds__(256) void k_abin(const int* __restrict__ src,
                                              const int* __restrict__ dst,
                                              const int* __restrict__ rel,
                                              const float* __restrict__ norm,
                                              int* __restrict__ gcnt,
                                              int2* __restrict__ bedges) {
    __shared__ int lcnt[NBUK], lbase[NBUK], lpos[NBUK];
    for (int i = threadIdx.x; i < NBUK; i += 256) { lcnt[i] = 0; lpos[i] = 0; }
    __syncthreads();

    const int e0 = blockIdx.x * ACHUNK;
    for (int e = e0 + threadIdx.x; e < e0 + ACHUNK; e += 256)
        atomicAdd(&lcnt[dst[e] >> 6], 1);
    __syncthreads();

    for (int i = threadIdx.x; i < NBUK; i += 256)
        lbase[i] = atomicAdd(&gcnt[i], lcnt[i]);
    __syncthreads();

    for (int e = e0 + threadIdx.x; e < e0 + ACHUNK; e += 256) {
        const int dv  = dst[e];
        const int bkt = dv >> 6;
        const int k   = atomicAdd(&lpos[bkt], 1);
        int idx = lbase[bkt] + k;
        idx = min(idx, BUKCAP - 1);                       // OOB guard (~1e-15)
        bedges[(size_t)bkt * BUKCAP + idx] =
            make_int2(((dv & 63) << 19) | (src[e] * 9 + rel[e]),
                      __float_as_int(norm[e]));
    }
}

// ---------------------------------------------------------------------------
// Phase B + epilogue: one block per bucket. Accumulate messages into a 64x64
// f32 LDS tile (ds_add_f32, conflict-free), then fuse self-loop + bias + ReLU
// and write out coalesced. Replaces BOTH the slot-fill (55us) and the gather:
// all f32 scatter now happens in LDS.
// ---------------------------------------------------------------------------
__global__ __launch_bounds__(256) void k_agg(const unsigned short* __restrict__ hw2,
                                             const int2* __restrict__ bedges,
                                             const int* __restrict__ gcnt,
                                             const float* __restrict__ bias,
                                             float* __restrict__ out) {
    const int b    = blockIdx.x;
    const int lane = threadIdx.x & 63;
    const int wv   = threadIdx.x >> 6;

    __shared__ float lt[NPB * 64];   // 16 KB
    for (int i = threadIdx.x; i < NPB * 64; i += 256) lt[i] = 0.f;
    __syncthreads();

    const int  nb = min(gcnt[b], BUKCAP);
    const int2* be = bedges + (size_t)b * BUKCAP;

    // 4-deep unrolled edge loop (waves stride 4): 4 gathers in flight.
    int e = wv;
    for (; e + 12 < nb; e += 16) {
        const int2 r0 = be[e];
        const int2 r1 = be[e + 4];
        const int2 r2 = be[e + 8];
        const int2 r3 = be[e + 12];
        const float v0 = bf2f(hw2[(size_t)(r0.x & 0x7FFFF) * 64 + lane]);
        const float v1 = bf2f(hw2[(size_t)(r1.x & 0x7FFFF) * 64 + lane]);
        const float v2 = bf2f(hw2[(size_t)(r2.x & 0x7FFFF) * 64 + lane]);
        const float v3 = bf2f(hw2[(size_t)(r3.x & 0x7FFFF) * 64 + lane]);
        atomicAdd(&lt[((unsigned)r0.x >> 19) * 64 + lane], v0 * __int_as_float(r0.y));
        atomicAdd(&lt[((unsigned)r1.x >> 19) * 64 + lane], v1 * __int_as_float(r1.y));
        atomicAdd(&lt[((unsigned)r2.x >> 19) * 64 + lane], v2 * __int_as_float(r2.y));
        atomicAdd(&lt[((unsigned)r3.x >> 19) * 64 + lane], v3 * __int_as_float(r3.y));
    }
    for (; e < nb; e += 4) {
        const int2 r = be[e];
        const float v = bf2f(hw2[(size_t)(r.x & 0x7FFFF) * 64 + lane]);
        atomicAdd(&lt[((unsigned)r.x >> 19) * 64 + lane], v * __int_as_float(r.y));
    }
    __syncthreads();

    // epilogue: out = relu(agg + bias + selfloop)
    const float bv = bias[lane];
    const int nbase = b * NPB;
    for (int rl = wv; rl < NPB; rl += 4) {
        const int n = nbase + rl;
        if (n >= N_NODES) break;
        const float v = lt[rl * 64 + lane] + bv
                      + bf2f(hw2[(size_t)n * NCOL + 512 + lane]);
        out[(size_t)n * 64 + lane] = fmaxf(v, 0.f);
    }
}

// ---------------------------------------------------------------------------
// Fallback path (ws too small): per-edge direct matvec + f32 atomics + finish.
// ---------------------------------------------------------------------------
__global__ __launch_bounds__(256) void k_edge_direct(const float* __restrict__ h,
                                                     const float* __restrict__ W,
                                                     const int* __restrict__ src,
                                                     const int* __restrict__ dst,
                                                     const int* __restrict__ rel,
                                                     const float* __restrict__ norm,
                                                     float* __restrict__ agg) {
    const int lane  = threadIdx.x & 63;
    const int warp  = (blockIdx.x * 256 + threadIdx.x) >> 6;
    const int nwarp = (gridDim.x * 256) >> 6;
    for (int e = warp; e < N_EDGES; e += nwarp) {
        const int   s  = src[e];
        const int   d2 = dst[e];
        const int   rr = rel[e];
        const float nm = norm[e];
        const float4* hp = (const float4*)(h + (size_t)s * 64);
        const float*  Wr = W + (size_t)rr * 4096;
        float acc = 0.f;
#pragma unroll
        for (int q = 0; q < 16; ++q) {
            float4 hv = hp[q];
            acc += hv.x * Wr[(4 * q + 0) * 64 + lane];
            acc += hv.y * Wr[(4 * q + 1) * 64 + lane];
            acc += hv.z * Wr[(4 * q + 2) * 64 + lane];
            acc += hv.w * Wr[(4 * q + 3) * 64 + lane];
        }
        atomicAdd(&agg[(size_t)d2 * 64 + lane], acc * nm);
    }
}

__global__ __launch_bounds__(256) void k_final(float* __restrict__ out,
                                               const float* __restrict__ h,
                                               const float* __restrict__ lw,
                                               const float* __restrict__ bias) {
    __shared__ float lws[4096];
    for (int i = threadIdx.x; i < 4096; i += 256) lws[i] = lw[i];
    __syncthreads();
    const int lane  = threadIdx.x & 63;
    const int warp  = (blockIdx.x * 256 + threadIdx.x) >> 6;
    const int nwarp = (gridDim.x * 256) >> 6;
    const float b = bias[lane];
    for (int n = warp; n < N_NODES; n += nwarp) {
        const float4* hp = (const float4*)(h + (size_t)n * 64);
        float acc = b;
#pragma unroll
        for (int q = 0; q < 16; ++q) {
            float4 hv = hp[q];
            acc += hv.x * lws[(4 * q + 0) * 64 + lane];
            acc += hv.y * lws[(4 * q + 1) * 64 + lane];
            acc += hv.z * lws[(4 * q + 2) * 64 + lane];
            acc += hv.w * lws[(4 * q + 3) * 64 + lane];
        }
        const size_t idx = (size_t)n * 64 + lane;
        const float v = out[idx] + acc;
        out[idx] = v > 0.f ? v : 0.f;
    }
}

extern "C" void kernel_launch(void* const* d_in, const int* in_sizes, int n_in,
                              void* d_out, int out_size, void* d_ws, size_t ws_size,
                              hipStream_t stream) {
    const float* h    = (const float*)d_in[0];
    const float* norm = (const float*)d_in[1];
    const float* W    = (const float*)d_in[2];
    const float* lw   = (const float*)d_in[3];
    const float* bias = (const float*)d_in[4];
    const int*   src  = (const int*)d_in[5];
    const int*   dst  = (const int*)d_in[6];
    const int*   rel  = (const int*)d_in[7];
    float* out = (float*)d_out;

    // --- workspace layout -------------------------------------------------
    char* ws = (char*)d_ws;
    unsigned short* hw2 = (unsigned short*)ws;                 // 50000*576 bf16 = 57.6 MB
    int2* bedges = (int2*)(ws + (size_t)N_NODES * NCOL * 2);   // 782*1280 int2 = 8.0 MB
    int*  gcnt   = (int*)(bedges + (size_t)NBUK * BUKCAP);     // 782 ints
    unsigned short* Bpack = (unsigned short*)(gcnt + NBUK + 16);  // 36864 bf16
    const size_t need = (size_t)((char*)(Bpack + BPACK_ELEMS) - ws);

    if (ws_size >= need) {
        k_bpack<<<196, 256, 0, stream>>>(W, lw, Bpack, gcnt);
        k_hw<<<NTILE, 256, 0, stream>>>(h, Bpack, hw2);
        k_abin<<<ABLK, 256, 0, stream>>>(src, dst, rel, norm, gcnt, bedges);
        k_agg<<<NBUK, 256, 0, stream>>>(hw2, bedges, gcnt, bias, out);
    } else {
        // fallback: atomic scatter path
        hipMemsetAsync(out, 0, (size_t)out_size * sizeof(float), stream);
        k_edge_direct<<<2048, 256, 0, stream>>>(h, W, src, dst, rel, norm, out);
        k_final<<<1024, 256, 0, stream>>>(out, h, lw, bias);
    }
}

// Round 12
// 82.445 us; speedup vs baseline: 4.8569x; 4.8569x over previous
//
#include <hip/hip_runtime.h>

#define N_NODES 50000
#define N_EDGES 800000
#define N_RELS  8
#define NCOL    576          // 9 * 64 output cols (8 relations + self-loop)
#define MAXDEG  64
#define BPACK_ELEMS (NCOL * 64)                          // 36864 bf16
#define NTILE   (N_NODES / 16)     // 3125 hw tiles

// bucketing: 64 nodes per bucket, bucket = dst >> 6
#define NBUK    782                // 782*64 = 50048 >= 50000
#define BUKCAP  1280               // lambda=1023, sigma~32 -> +8 sigma
#define ABLK    256                // abin blocks
#define ATHR    512
#define ACHUNK  3125               // 256 * 3125 = 800000 exactly

typedef __attribute__((ext_vector_type(8))) short short8;
typedef __attribute__((ext_vector_type(4))) float f32x4;

static __device__ __forceinline__ short f2bf(float f) {
    unsigned u = __float_as_uint(f);
    unsigned r = (u + 0x7FFFu + ((u >> 16) & 1u)) >> 16;   // RNE
    return (short)r;
}
static __device__ __forceinline__ float bf2f(unsigned short b) {
    return __uint_as_float(((unsigned)b) << 16);
}

// ---------------------------------------------------------------------------
// Pre-pack B (8 rels + self-loop) into MFMA fragment order; also zeroes gcnt.
// ---------------------------------------------------------------------------
__global__ __launch_bounds__(256) void k_bpack(const float* __restrict__ W,
                                               const float* __restrict__ lw,
                                               unsigned short* __restrict__ Bpack,
                                               int* __restrict__ gcnt) {
    const int id = blockIdx.x * 256 + threadIdx.x;
    if (id < NBUK) gcnt[id] = 0;
    if (id >= BPACK_ELEMS) return;
    const int e    = id & 7;
    const int lane = (id >> 3) & 63;
    const int g    = id >> 9;            // 0..71
    const int w    = g / 18;
    const int r18  = g - w * 18;
    const int t    = r18 >> 1;
    const int s    = r18 & 1;
    const int c0   = w * 144 + t * 16;
    const int rel  = c0 >> 6;
    const int cc   = (c0 & 63) + (lane & 15);
    const int kk   = s * 32 + (lane >> 4) * 8 + e;
    const float* Bp = (rel < 8) ? (W + (size_t)rel * 4096) : lw;
    Bpack[id] = (unsigned short)f2bf(Bp[(size_t)kk * 64 + cc]);
}

// ---------------------------------------------------------------------------
// MFMA transform: hw2[n][c] = sum_d h[n][d] * B[d][c]. One 16-node tile per
// block, grid = 3125. (Proven round-6 structure.)
// ---------------------------------------------------------------------------
__global__ __launch_bounds__(256) void k_hw(const float* __restrict__ h,
                                            const unsigned short* __restrict__ Bpack,
                                            unsigned short* __restrict__ hw2) {
    const int lane  = threadIdx.x & 63;
    const int w     = threadIdx.x >> 6;
    const int l15   = lane & 15;
    const int lg    = lane >> 4;           // 0..3
    const int wcol0 = w * 144;
    const int n0    = blockIdx.x * 16;

    short8 barr[9][2];
#pragma unroll
    for (int t = 0; t < 9; ++t)
#pragma unroll
        for (int s = 0; s < 2; ++s)
            barr[t][s] = *(const short8*)(Bpack + ((size_t)(w * 18 + t * 2 + s) * 64 + lane) * 8);

    short8 afr[2];
    const float* hp = h + (size_t)(n0 + l15) * 64 + lg * 8;
#pragma unroll
    for (int s = 0; s < 2; ++s) {
        const float4 x = *(const float4*)(hp + s * 32);
        const float4 y = *(const float4*)(hp + s * 32 + 4);
        short8 a;
        a[0] = f2bf(x.x); a[1] = f2bf(x.y); a[2] = f2bf(x.z); a[3] = f2bf(x.w);
        a[4] = f2bf(y.x); a[5] = f2bf(y.y); a[6] = f2bf(y.z); a[7] = f2bf(y.w);
        afr[s] = a;
    }

    f32x4 acc[9];
#pragma unroll
    for (int t = 0; t < 9; ++t) {
        f32x4 c = {0.f, 0.f, 0.f, 0.f};
        c = __builtin_amdgcn_mfma_f32_16x16x32_bf16(afr[0], barr[t][0], c, 0, 0, 0);
        c = __builtin_amdgcn_mfma_f32_16x16x32_bf16(afr[1], barr[t][1], c, 0, 0, 0);
        acc[t] = c;
    }

    __shared__ unsigned short lds[16 * NCOL];   // 18.4 KB
#pragma unroll
    for (int t = 0; t < 9; ++t) {
        const int c = wcol0 + t * 16 + l15;
#pragma unroll
        for (int r = 0; r < 4; ++r) {
            const int row = lg * 4 + r;   // D: col=lane&15, row=lg*4+reg
            lds[row * NCOL + (c ^ (lg << 4))] = (unsigned short)f2bf(acc[t][r]);
        }
    }
    __syncthreads();

    const unsigned* ldsu = (const unsigned*)lds;       // pitch 288 u32
    unsigned* outu = (unsigned*)hw2;
#pragma unroll
    for (int i = threadIdx.x; i < 16 * 288; i += 256) {
        const int row = i / 288;
        const int cu  = i - row * 288;
        outu[(size_t)(n0 + row) * 288 + cu] = ldsu[row * 288 + (cu ^ ((row >> 2) << 3))];
    }
}

// ---------------------------------------------------------------------------
// Phase A: bucket-bin edges by dst>>6. Per block: LDS count -> one global
// atomic per (block,bucket) reserving a CONTIGUOUS run -> place. The 8B
// scatter becomes ~32-64B runs inside an 8MB array (L2-assemblable), killing
// the one-line-per-record thrash (rounds 7-10: WRITE pinned ~106MB).
// rec.x = (dst&63)<<19 | (src*9+rel); rec.y = norm bits.
// ---------------------------------------------------------------------------
__global__ __launch_bounds__(ATHR) void k_abin(const int* __restrict__ src,
                                               const int* __restrict__ dst,
                                               const int* __restrict__ rel,
                                               const float* __restrict__ norm,
                                               int* __restrict__ gcnt,
                                               int2* __restrict__ bedges) {
    __shared__ int lcnt[NBUK], lbase[NBUK], lpos[NBUK];
    for (int i = threadIdx.x; i < NBUK; i += ATHR) { lcnt[i] = 0; lpos[i] = 0; }
    __syncthreads();

    const int e0 = blockIdx.x * ACHUNK;
    for (int e = e0 + threadIdx.x; e < e0 + ACHUNK; e += ATHR)
        atomicAdd(&lcnt[dst[e] >> 6], 1);
    __syncthreads();

    for (int i = threadIdx.x; i < NBUK; i += ATHR)
        lbase[i] = atomicAdd(&gcnt[i], lcnt[i]);
    __syncthreads();

    for (int e = e0 + threadIdx.x; e < e0 + ACHUNK; e += ATHR) {
        const int dv  = dst[e];
        const int bkt = dv >> 6;
        int idx = lbase[bkt] + atomicAdd(&lpos[bkt], 1);
        idx = min(idx, BUKCAP - 1);                       // OOB guard (~1e-15)
        bedges[(size_t)bkt * BUKCAP + idx] =
            make_int2(((dv & 63) << 19) | (src[e] * 9 + rel[e]),
                      __float_as_int(norm[e]));
    }
}

// ---------------------------------------------------------------------------
// Phase B: one block per bucket, ONE pass, no serial chains. Read the
// bucket's recs coalesced, slot each into payload[node*64+pos] via a 64-int
// LDS counter. All stores land in the bucket's 32KB slot region -> one XCD's
// L2 assembles the lines. Writes cnt[] for the gather.
// ---------------------------------------------------------------------------
__global__ __launch_bounds__(256) void k_bsort(const int2* __restrict__ bedges,
                                               const int* __restrict__ gcnt,
                                               int2* __restrict__ payload,
                                               int* __restrict__ cnt) {
    __shared__ int lc[64];
    if (threadIdx.x < 64) lc[threadIdx.x] = 0;
    __syncthreads();

    const int b     = blockIdx.x;
    const int nb    = min(gcnt[b], BUKCAP);
    const int nbase = b * 64;
    const int2* be  = bedges + (size_t)b * BUKCAP;

    for (int i = threadIdx.x; i < nb; i += 256) {
        const int2 r = be[i];
        const int  d = (unsigned)r.x >> 19;
        const int  pos = atomicAdd(&lc[d], 1) & (MAXDEG - 1);
        payload[(size_t)(nbase + d) * MAXDEG + pos] =
            make_int2(r.x & 0x7FFFF, r.y);
    }
    __syncthreads();

    if (threadIdx.x < 64) {
        const int n = nbase + threadIdx.x;
        if (n < N_NODES) cnt[n] = lc[threadIdx.x];
    }
}

// ---------------------------------------------------------------------------
// Gather: one wave per node. 8-wide unroll, int4 payload loads (2 edges/load),
// 4 accumulator chains -> 8 concurrent hw2 gathers in flight. (Proven 12us.)
// ---------------------------------------------------------------------------
__global__ __launch_bounds__(256) void k_gather(const unsigned short* __restrict__ hw2,
                                                const int* __restrict__ cnt,
                                                const int2* __restrict__ payload,
                                                const float* __restrict__ bias,
                                                float* __restrict__ out) {
    const int lane = threadIdx.x & 63;
    const int n = (blockIdx.x * 256 + threadIdx.x) >> 6;
    if (n >= N_NODES) return;
    const int deg = min(cnt[n], MAXDEG);
    const int2* pl  = payload + (size_t)n * MAXDEG;
    const int4* pl4 = (const int4*)pl;                 // 16B-aligned (n*512B)

    float a0 = bias[lane] + bf2f(hw2[(size_t)n * NCOL + 512 + lane]);  // self-loop
    float a1 = 0.f, a2 = 0.f, a3 = 0.f;
    int t = 0;
    for (; t + 8 <= deg; t += 8) {
        const int4 q0 = pl4[(t >> 1) + 0];
        const int4 q1 = pl4[(t >> 1) + 1];
        const int4 q2 = pl4[(t >> 1) + 2];
        const int4 q3 = pl4[(t >> 1) + 3];
        const float v0 = bf2f(hw2[(size_t)q0.x * 64 + lane]);
        const float v1 = bf2f(hw2[(size_t)q0.z * 64 + lane]);
        const float v2 = bf2f(hw2[(size_t)q1.x * 64 + lane]);
        const float v3 = bf2f(hw2[(size_t)q1.z * 64 + lane]);
        const float v4 = bf2f(hw2[(size_t)q2.x * 64 + lane]);
        const float v5 = bf2f(hw2[(size_t)q2.z * 64 + lane]);
        const float v6 = bf2f(hw2[(size_t)q3.x * 64 + lane]);
        const float v7 = bf2f(hw2[(size_t)q3.z * 64 + lane]);
        a0 += v0 * __int_as_float(q0.y);
        a1 += v1 * __int_as_float(q0.w);
        a2 += v2 * __int_as_float(q1.y);
        a3 += v3 * __int_as_float(q1.w);
        a0 += v4 * __int_as_float(q2.y);
        a1 += v5 * __int_as_float(q2.w);
        a2 += v6 * __int_as_float(q3.y);
        a3 += v7 * __int_as_float(q3.w);
    }
    for (; t + 2 <= deg; t += 2) {
        const int4 q = pl4[t >> 1];
        a0 += bf2f(hw2[(size_t)q.x * 64 + lane]) * __int_as_float(q.y);
        a1 += bf2f(hw2[(size_t)q.z * 64 + lane]) * __int_as_float(q.w);
    }
    if (t < deg) {
        const int2 p = pl[t];
        a0 += bf2f(hw2[(size_t)p.x * 64 + lane]) * __int_as_float(p.y);
    }
    out[(size_t)n * 64 + lane] = fmaxf((a0 + a1) + (a2 + a3), 0.f);
}

// ---------------------------------------------------------------------------
// Fallback path (ws too small): per-edge direct matvec + f32 atomics + finish.
// ---------------------------------------------------------------------------
__global__ __launch_bounds__(256) void k_edge_direct(const float* __restrict__ h,
                                                     const float* __restrict__ W,
                                                     const int* __restrict__ src,
                                                     const int* __restrict__ dst,
                                                     const int* __restrict__ rel,
                                                     const float* __restrict__ norm,
                                                     float* __restrict__ agg) {
    const int lane  = threadIdx.x & 63;
    const int warp  = (blockIdx.x * 256 + threadIdx.x) >> 6;
    const int nwarp = (gridDim.x * 256) >> 6;
    for (int e = warp; e < N_EDGES; e += nwarp) {
        const int   s  = src[e];
        const int   d2 = dst[e];
        const int   rr = rel[e];
        const float nm = norm[e];
        const float4* hp = (const float4*)(h + (size_t)s * 64);
        const float*  Wr = W + (size_t)rr * 4096;
        float acc = 0.f;
#pragma unroll
        for (int q = 0; q < 16; ++q) {
            float4 hv = hp[q];
            acc += hv.x * Wr[(4 * q + 0) * 64 + lane];
            acc += hv.y * Wr[(4 * q + 1) * 64 + lane];
            acc += hv.z * Wr[(4 * q + 2) * 64 + lane];
            acc += hv.w * Wr[(4 * q + 3) * 64 + lane];
        }
        atomicAdd(&agg[(size_t)d2 * 64 + lane], acc * nm);
    }
}

__global__ __launch_bounds__(256) void k_final(float* __restrict__ out,
                                               const float* __restrict__ h,
                                               const float* __restrict__ lw,
                                               const float* __restrict__ bias) {
    __shared__ float lws[4096];
    for (int i = threadIdx.x; i < 4096; i += 256) lws[i] = lw[i];
    __syncthreads();
    const int lane  = threadIdx.x & 63;
    const int warp  = (blockIdx.x * 256 + threadIdx.x) >> 6;
    const int nwarp = (gridDim.x * 256) >> 6;
    const float b = bias[lane];
    for (int n = warp; n < N_NODES; n += nwarp) {
        const float4* hp = (const float4*)(h + (size_t)n * 64);
        float acc = b;
#pragma unroll
        for (int q = 0; q < 16; ++q) {
            float4 hv = hp[q];
            acc += hv.x * lws[(4 * q + 0) * 64 + lane];
            acc += hv.y * lws[(4 * q + 1) * 64 + lane];
            acc += hv.z * lws[(4 * q + 2) * 64 + lane];
            acc += hv.w * lws[(4 * q + 3) * 64 + lane];
        }
        const size_t idx = (size_t)n * 64 + lane;
        const float v = out[idx] + acc;
        out[idx] = v > 0.f ? v : 0.f;
    }
}

extern "C" void kernel_launch(void* const* d_in, const int* in_sizes, int n_in,
                              void* d_out, int out_size, void* d_ws, size_t ws_size,
                              hipStream_t stream) {
    const float* h    = (const float*)d_in[0];
    const float* norm = (const float*)d_in[1];
    const float* W    = (const float*)d_in[2];
    const float* lw   = (const float*)d_in[3];
    const float* bias = (const float*)d_in[4];
    const int*   src  = (const int*)d_in[5];
    const int*   dst  = (const int*)d_in[6];
    const int*   rel  = (const int*)d_in[7];
    float* out = (float*)d_out;

    // --- workspace layout -------------------------------------------------
    char* ws = (char*)d_ws;
    unsigned short* hw2 = (unsigned short*)ws;                  // 57.6 MB
    int2* bedges  = (int2*)(ws + (size_t)N_NODES * NCOL * 2);   // 782*1280*8 = 8.0 MB
    int2* payload = bedges + (size_t)NBUK * BUKCAP;             // 50000*64*8 = 25.6 MB
    int*  gcnt    = (int*)(payload + (size_t)N_NODES * MAXDEG); // 782
    int*  cnt     = gcnt + NBUK + 16;                           // 50000
    unsigned short* Bpack = (unsigned short*)(cnt + N_NODES + 16);
    const size_t need = (size_t)((char*)(Bpack + BPACK_ELEMS) - ws);

    if (ws_size >= need) {
        k_bpack<<<196, 256, 0, stream>>>(W, lw, Bpack, gcnt);
        k_hw<<<NTILE, 256, 0, stream>>>(h, Bpack, hw2);
        k_abin<<<ABLK, ATHR, 0, stream>>>(src, dst, rel, norm, gcnt, bedges);
        k_bsort<<<NBUK, 256, 0, stream>>>(bedges, gcnt, payload, cnt);
        k_gather<<<(N_NODES + 3) / 4, 256, 0, stream>>>(hw2, cnt, payload, bias, out);
    } else {
        // fallback: atomic scatter path
        hipMemsetAsync(out, 0, (size_t)out_size * sizeof(float), stream);
        k_edge_direct<<<2048, 256, 0, stream>>>(h, W, src, dst, rel, norm, out);
        k_final<<<1024, 256, 0, stream>>>(out, h, lw, bias);
    }
}